// Round 4
// baseline (348.362 us; speedup 1.0000x reference)
//
#include <hip/hip_runtime.h>
#include <math.h>

// Fast guided filter, fully fused, FP64 internal math (fp64 margin vs fp32 ref
// is what keeps absmax at the passing 1.0 -> do NOT reduce precision).
// Round-7: LDS-free column-band rewrite.
// Round-6 post-mortem: kernel ~96us; LDS pipe ~80% busy (2a writes + 2b reads
// + stage-3 re-reads ~2000 cyc/block x 96 blocks/CU) co-dominant with fp64
// issue (~32us); 3 barriers serialize. Fix: eliminate LDS + barriers.
//   - Each thread owns 2 adjacent output cols, marches down TY=16 rows.
//   - Horizontal stencils in-thread: 6 sum-columns per 2 outputs.
//   - Vertical stencils via rolling registers: 3 raw pixel rows (f32) and
//     3 rows of {L,R,F} horizontal combos of A,b (f64), rotated with
//     compile-time slot indices (3-phase unroll; rule #20: no dynamic idx).
//   - 1-row load-ahead (xn/yn) so global loads have a full step (~1000cyc)
//     to land; SGPR row base + precomputed clamped col offsets.
//   - A,b zeroed outside image (directional conv zero-pads); pixel reads
//     replicate-clamped (box filter edge-pads) -- matches reference.

#define BX 512
#define TY 16     // loop structure below hardcodes TY=16 (5 triples + tail)
#define NT 256

__device__ __forceinline__ double fast_rcp(double v) {
#if __has_builtin(__builtin_amdgcn_rcp)
    double r = __builtin_amdgcn_rcp(v);     // v_rcp_f64, ~29-bit
#else
    double r = 1.0 / v;
#endif
    double e = fma(-v, r, 1.0);             // Newton 1 -> ~53-bit
    r = fma(r, e, r);
    e = fma(-v, r, 1.0);                    // Newton 2 -> ~1 ulp
    r = fma(r, e, r);
    return r;
}

__device__ __forceinline__ int iclamp(int v, int lo, int hi) {
    return v < lo ? lo : (v > hi ? hi : v);
}

// One pipeline step. P = register-slot phase (= S%3, compile-time).
// Commits prefetched pixel row y0+S, prefetches row y0+S+1, computes A-row
// ar = y0+S-1 (cols c0-1..c0+2), pushes {L,R,F} combos, emits output row ar-1.
template <int P, bool EMIT, bool PREF>
__device__ __forceinline__ void fgf_step(
    int S, int y0, int c0, int H, int W,
    const float* __restrict__ xc, const float* __restrict__ yc,
    float* __restrict__ oc,
    const int (&coli)[6], const bool (&av)[4],
    float (&xr)[3][6], float (&yr)[3][6],
    float (&xn)[6], float (&yn)[6],
    double (&CA)[3][2][3], double (&CB)[3][2][3])
{
    const double EPS81 = 81.0 * 1.0e-4;
    const double INV9  = 1.0 / 9.0;
    const double I6    = 1.0 / 6.0;
    constexpr int PO = (P + 1) % 3;   // oldest pixel row (= emit row ar-1)
    constexpr int PM = (P + 2) % 3;   // middle pixel row (= ar)

    // 1. commit prefetched row (y0+S) into slot P
#pragma unroll
    for (int k = 0; k < 6; k++) { xr[P][k] = xn[k]; yr[P][k] = yn[k]; }

    // 2. prefetch next row (uniform row base -> SGPR; per-lane col offsets)
    if (PREF) {
        int rn = y0 + S + 1; if (rn > H - 1) rn = H - 1;
        const float* __restrict__ pxn = xc + (size_t)rn * W;
        const float* __restrict__ pyn = yc + (size_t)rn * W;
#pragma unroll
        for (int k = 0; k < 6; k++) { xn[k] = pxn[coli[k]]; yn[k] = pyn[coli[k]]; }
    }

    const int ar = y0 + S - 1;

    // 3. vertical 3-row column sums at 6 columns
    double Sx[6], Sy[6], Sxy[6], Sxx[6];
#pragma unroll
    for (int k = 0; k < 6; k++) {
        double x0v = (double)xr[PO][k];
        double x1v = (double)xr[PM][k];
        double x2v = (double)xr[P][k];
        double y0v = (double)yr[PO][k];
        double y1v = (double)yr[PM][k];
        double y2v = (double)yr[P][k];
        Sx[k]  = (x0v + x1v) + x2v;
        Sy[k]  = (y0v + y1v) + y2v;
        Sxy[k] = fma(x2v, y2v, fma(x1v, y1v, x0v * y0v));
        Sxx[k] = fma(x2v, x2v, fma(x1v, x1v, x0v * x0v));
    }

    // 4. A,b at 4 A-columns (zero outside image: directional conv zero-pads)
    const bool rvalid = (ar >= 0) && (ar < H);
    double Aj[4], Bj[4];
#pragma unroll
    for (int j = 0; j < 4; j++) {
        double sx3  = (Sx[j]  + Sx[j + 1])  + Sx[j + 2];
        double sy3  = (Sy[j]  + Sy[j + 1])  + Sy[j + 2];
        double sxy3 = (Sxy[j] + Sxy[j + 1]) + Sxy[j + 2];
        double sxx3 = (Sxx[j] + Sxx[j + 1]) + Sxx[j + 2];
        double num = fma(9.0, sxy3, -(sx3 * sy3));            // 9*cov*9
        double den = fma(-sx3, sx3, fma(9.0, sxx3, EPS81));   // 9*(var+eps)*9
        double Av = num * fast_rcp(den);
        double Bv = fma(-Av, sx3, sy3) * INV9;
        bool ok = rvalid && av[j];
        Aj[j] = ok ? Av : 0.0;
        Bj[j] = ok ? Bv : 0.0;
    }

    // 5. horizontal {L,R,F} combos for the 2 output cols -> slot P
#pragma unroll
    for (int i = 0; i < 2; i++) {
        double l = Aj[i] + Aj[i + 1], r = Aj[i + 1] + Aj[i + 2];
        CA[P][i][0] = l; CA[P][i][1] = r; CA[P][i][2] = l + Aj[i + 2];
        l = Bj[i] + Bj[i + 1]; r = Bj[i + 1] + Bj[i + 2];
        CB[P][i][0] = l; CB[P][i][1] = r; CB[P][i][2] = l + Bj[i + 2];
    }

    // 6. emit output row ar-1 from combo rows {PO=ar-2, PM=ar-1, P=ar}
    if (EMIT) {
        const int oy = ar - 1;
        if (oy < H) {
            float o0 = 0.0f, o1 = 0.0f;
#pragma unroll
            for (int i = 0; i < 2; i++) {
                double im  = (double)xr[PO][i + 2];   // pixel (oy, c0+i)
                double mim = -im;
                // directions: L,R,U,D,NW,NE,SW,SE (same order + first-min ties)
                double nwA = CA[PO][i][0] + CA[PM][i][0];
                double neA = CA[PO][i][1] + CA[PM][i][1];
                double sa[8] = {
                    nwA + CA[P][i][0],                 // L
                    neA + CA[P][i][1],                 // R
                    CA[PO][i][2] + CA[PM][i][2],       // U
                    CA[PM][i][2] + CA[P][i][2],        // D
                    nwA,                               // NW
                    neA,                               // NE
                    CA[PM][i][0] + CA[P][i][0],        // SW
                    CA[PM][i][1] + CA[P][i][1]         // SE
                };
                double nwB = CB[PO][i][0] + CB[PM][i][0];
                double neB = CB[PO][i][1] + CB[PM][i][1];
                double sb[8] = {
                    nwB + CB[P][i][0],
                    neB + CB[P][i][1],
                    CB[PO][i][2] + CB[PM][i][2],
                    CB[PM][i][2] + CB[P][i][2],
                    nwB,
                    neB,
                    CB[PM][i][0] + CB[P][i][0],
                    CB[PM][i][1] + CB[P][i][1]
                };
                double best = 0.0;
#pragma unroll
                for (int q = 0; q < 8; q++) {
                    double wq = (q < 4) ? I6 : 0.25;
                    double dq = fma(wq, fma(sa[q], im, sb[q]), mim);
                    if (q == 0) best = dq;
                    else best = (fabs(dq) < fabs(best)) ? dq : best;
                }
                double res = trunc(best + im);
                res = fmin(fmax(res, 0.0), 255.0);
                if (i == 0) o0 = (float)res; else o1 = (float)res;
            }
            size_t ob = (size_t)oy * W + c0;
            if (c0 + 1 < W) {
                float2 o2; o2.x = o0; o2.y = o1;
                *reinterpret_cast<float2*>(&oc[ob]) = o2;
            } else if (c0 < W) {
                oc[ob] = o0;
            }
        }
    }
}

__global__ __launch_bounds__(NT, 2) void fgf_band_kernel(
    const float* __restrict__ x, const float* __restrict__ y,
    float* __restrict__ out, int H, int W)
{
    const int c   = blockIdx.z;
    const int bx0 = blockIdx.x * BX;
    const int y0  = blockIdx.y * TY;
    const size_t plane = (size_t)H * (size_t)W;
    const float* xc = x + (size_t)c * plane;
    const float* yc = y + (size_t)c * plane;
    float* oc = out + (size_t)c * plane;

    const int t  = threadIdx.y * 64 + threadIdx.x;
    const int c0 = bx0 + 2 * t;

    // loop-invariant clamped column byte-offsets + A-col validity
    int coli[6];
    bool av[4];
#pragma unroll
    for (int k = 0; k < 6; k++) coli[k] = iclamp(c0 - 2 + k, 0, W - 1);
#pragma unroll
    for (int j = 0; j < 4; j++) { int ax = c0 - 1 + j; av[j] = (ax >= 0) && (ax < W); }

    float  xr[3][6], yr[3][6], xn[6], yn[6];
    double CA[3][2][3], CB[3][2][3];   // written (S=0,1) before first read (S=2)

    // prologue: slot1 <- row y0-2, slot2 <- row y0-1, xn/yn <- row y0
    {
        int r1 = iclamp(y0 - 2, 0, H - 1);
        int r2 = iclamp(y0 - 1, 0, H - 1);
        const float* px1 = xc + (size_t)r1 * W;  const float* py1 = yc + (size_t)r1 * W;
        const float* px2 = xc + (size_t)r2 * W;  const float* py2 = yc + (size_t)r2 * W;
        const float* px3 = xc + (size_t)y0 * W;  const float* py3 = yc + (size_t)y0 * W;
#pragma unroll
        for (int k = 0; k < 6; k++) {
            xr[1][k] = px1[coli[k]]; yr[1][k] = py1[coli[k]];
            xr[2][k] = px2[coli[k]]; yr[2][k] = py2[coli[k]];
            xn[k]    = px3[coli[k]]; yn[k]    = py3[coli[k]];
        }
    }

    // pipeline: S=0..17; emit S=2..17 (output rows y0..y0+15)
    fgf_step<0, false, true>(0, y0, c0, H, W, xc, yc, oc, coli, av, xr, yr, xn, yn, CA, CB);
    fgf_step<1, false, true>(1, y0, c0, H, W, xc, yc, oc, coli, av, xr, yr, xn, yn, CA, CB);
#pragma unroll 1
    for (int sb = 0; sb < 5; sb++) {
        const int S2 = 2 + 3 * sb;
        fgf_step<2, true, true>(S2,     y0, c0, H, W, xc, yc, oc, coli, av, xr, yr, xn, yn, CA, CB);
        fgf_step<0, true, true>(S2 + 1, y0, c0, H, W, xc, yc, oc, coli, av, xr, yr, xn, yn, CA, CB);
        fgf_step<1, true, true>(S2 + 2, y0, c0, H, W, xc, yc, oc, coli, av, xr, yr, xn, yn, CA, CB);
    }
    fgf_step<2, true, false>(17, y0, c0, H, W, xc, yc, oc, coli, av, xr, yr, xn, yn, CA, CB);
}

extern "C" void kernel_launch(void* const* d_in, const int* in_sizes, int n_in,
                              void* d_out, int out_size, void* d_ws, size_t ws_size,
                              hipStream_t stream) {
    const float* lr_x = (const float*)d_in[0];
    const float* lr_y = (const float*)d_in[1];
    // d_in[2] (hr_x) is dead in the reference computation.
    float* out = (float*)d_out;

    const int plane = in_sizes[0] / 3;
    const int H = (int)(0.5 + sqrt((double)plane));
    const int W = plane / H;

    dim3 block(64, 4, 1);
    dim3 grid((W + BX - 1) / BX, (H + TY - 1) / TY, 3);
    fgf_band_kernel<<<grid, block, 0, stream>>>(lr_x, lr_y, out, H, W);
}

// Round 5
// 329.365 us; speedup vs baseline: 1.0577x; 1.0577x over previous
//
#include <hip/hip_runtime.h>
#include <math.h>

// Fast guided filter, fully fused, FP64 internal math (fp64 margin vs fp32 ref
// is what keeps absmax at the passing 1.0 -> do NOT reduce precision).
// Round-8: one-column-per-lane + DPP neighbor sharing (no LDS, no barriers).
// Round-7 post-mortem: LDS-free 2-col/thread was NEUTRAL (~99us) because the
// 6-S-col / 4-A-col per-thread redundancy (3x S, 2.25 rcp/output) ate the LDS
// savings. Fix: share across lanes with v_mov_b32_dpp wave_shr:1/wave_shl:1
// (VALU pipe): each lane owns ONE column -> vertical sums once, S3 via 16 b32
// DPP movs, ONE A,b (1 rcp/output), A,b neighbors via 8 DPP movs. ~75 fp64 +
// ~49 b32 ops/output vs ~165 fp64/output in round-7; 2 coalesced dword loads
// per step/lane vs 12. Formula order bit-identical to round-6/7 lineage.
// Wave = 64 lanes covers 60 output cols (lanes 0,1,62,63 are halo; their
// invalid shuffle results are never consumed by emitting lanes).

#define WCOLS 60
#define BCOLS (4 * WCOLS)   // 240 output cols per 256-thread block
#define TY 30               // output rows per block (9 triples + 3-step tail)
#define NT 256

__device__ __forceinline__ double fast_rcp(double v) {
#if __has_builtin(__builtin_amdgcn_rcp)
    double r = __builtin_amdgcn_rcp(v);     // v_rcp_f64, ~29-bit
#else
    double r = 1.0 / v;
#endif
    double e = fma(-v, r, 1.0);             // Newton 1 -> ~53-bit
    r = fma(r, e, r);
    e = fma(-v, r, 1.0);                    // Newton 2 -> ~1 ulp
    r = fma(r, e, r);
    return r;
}

__device__ __forceinline__ int iclamp(int v, int lo, int hi) {
    return v < lo ? lo : (v > hi ? hi : v);
}

// f64 whole-wave lane shift via two v_mov_b32_dpp. CDNA keeps gfx9 DPP wave_*
// controls (removed only in RDNA). bound_ctrl=true -> invalid lanes read 0;
// only halo lanes ever see that, and their results are never emitted.
template <int CTRL>
__device__ __forceinline__ double dpp_mov64(double v) {
    int lo = __double2loint(v);
    int hi = __double2hiint(v);
    lo = __builtin_amdgcn_mov_dpp(lo, CTRL, 0xF, 0xF, true);
    hi = __builtin_amdgcn_mov_dpp(hi, CTRL, 0xF, 0xF, true);
    return __hiloint2double(hi, lo);
}
// dst[lane] = src[lane-1]  (WAVE_SHR:1 = 0x138)
__device__ __forceinline__ double nbr_left(double v)  { return dpp_mov64<0x138>(v); }
// dst[lane] = src[lane+1]  (WAVE_SHL:1 = 0x130)
__device__ __forceinline__ double nbr_right(double v) { return dpp_mov64<0x130>(v); }

// One pipeline step, phase P = S%3 (compile-time). Commits prefetched pixel
// row y0+S into slot P, prefetches row y0+S+1, computes A,b at row ar=y0+S-1
// for this lane's column, pushes {L,R,F} combos into combo slot P, and emits
// output row ar-1 from combo rows {PO=ar-2, PM=ar-1, P=ar}.
template <int P, bool EMIT, bool PREF>
__device__ __forceinline__ void fgf_step(
    int S, int y0, int H, int W,
    int coli, bool colv, bool outv, int dc,
    const float* __restrict__ xc, const float* __restrict__ yc,
    float* __restrict__ oc,
    double (&X)[3], double (&Y)[3], float& xn, float& yn,
    double (&CA)[3][3], double (&CB)[3][3])
{
    const double EPS81 = 81.0 * 1.0e-4;
    const double INV9  = 1.0 / 9.0;
    const double I6    = 1.0 / 6.0;
    constexpr int PO = (P + 1) % 3;   // oldest pixel row (= emit row ar-1)
    constexpr int PM = (P + 2) % 3;   // middle pixel row (= ar)

    // 1. commit prefetched row (y0+S) into slot P
    X[P] = (double)xn;
    Y[P] = (double)yn;

    // 2. prefetch next row (uniform row base; lane-consecutive cols -> coalesced)
    if (PREF) {
        int rn = y0 + S + 1; if (rn > H - 1) rn = H - 1;
        xn = xc[(size_t)rn * W + coli];
        yn = yc[(size_t)rn * W + coli];
    }

    const int ar = y0 + S - 1;

    // 3. vertical 3-row sums for this lane's column (same op order as r6/r7)
    double Sx  = (X[PO] + X[PM]) + X[P];
    double Sy  = (Y[PO] + Y[PM]) + Y[P];
    double Sxy = fma(X[P], Y[P], fma(X[PM], Y[PM], X[PO] * Y[PO]));
    double Sxx = fma(X[P], X[P], fma(X[PM], X[PM], X[PO] * X[PO]));

    // 4. horizontal 3-col sums via DPP neighbors: (left + center) + right
    double Sx3  = (nbr_left(Sx)  + Sx)  + nbr_right(Sx);
    double Sy3  = (nbr_left(Sy)  + Sy)  + nbr_right(Sy);
    double Sxy3 = (nbr_left(Sxy) + Sxy) + nbr_right(Sxy);
    double Sxx3 = (nbr_left(Sxx) + Sxx) + nbr_right(Sxx);

    // 5. A,b at (ar, dc); zero outside image (directional conv zero-pads)
    double num = fma(9.0, Sxy3, -(Sx3 * Sy3));            // 9*cov*9
    double den = fma(-Sx3, Sx3, fma(9.0, Sxx3, EPS81));   // 9*(var+eps)*9
    double Av = num * fast_rcp(den);
    double Bv = fma(-Av, Sx3, Sy3) * INV9;
    bool ok = colv && (ar >= 0) && (ar < H);
    Av = ok ? Av : 0.0;
    Bv = ok ? Bv : 0.0;

    // 6. neighbor A,b + horizontal {L,R,F} combos -> combo slot P
    double Al = nbr_left(Av), Ar = nbr_right(Av);
    double Bl = nbr_left(Bv), Br = nbr_right(Bv);
    {
        double l = Al + Av, r = Av + Ar;
        CA[P][0] = l; CA[P][1] = r; CA[P][2] = l + Ar;
        l = Bl + Bv; r = Bv + Br;
        CB[P][0] = l; CB[P][1] = r; CB[P][2] = l + Br;
    }

    // 7. emit output row ar-1
    if (EMIT) {
        const int oy = ar - 1;
        if (oy < H) {
            double im  = X[PO];       // pixel (oy, dc) as double (exact cvt)
            double mim = -im;

            // directions: L,R,U,D,NW,NE,SW,SE (same order + first-min ties)
            double nwA = CA[PO][0] + CA[PM][0];
            double neA = CA[PO][1] + CA[PM][1];
            double sa[8] = {
                nwA + CA[P][0],               // L
                neA + CA[P][1],               // R
                CA[PO][2] + CA[PM][2],        // U
                CA[PM][2] + CA[P][2],         // D
                nwA,                          // NW
                neA,                          // NE
                CA[PM][0] + CA[P][0],         // SW
                CA[PM][1] + CA[P][1]          // SE
            };
            double nwB = CB[PO][0] + CB[PM][0];
            double neB = CB[PO][1] + CB[PM][1];
            double sb[8] = {
                nwB + CB[P][0],
                neB + CB[P][1],
                CB[PO][2] + CB[PM][2],
                CB[PM][2] + CB[P][2],
                nwB,
                neB,
                CB[PM][0] + CB[P][0],
                CB[PM][1] + CB[P][1]
            };

            double best = 0.0;
#pragma unroll
            for (int q = 0; q < 8; q++) {
                double wq = (q < 4) ? I6 : 0.25;
                double dq = fma(wq, fma(sa[q], im, sb[q]), mim);
                if (q == 0) best = dq;
                else best = (fabs(dq) < fabs(best)) ? dq : best;
            }

            double res = trunc(best + im);
            res = fmin(fmax(res, 0.0), 255.0);
            if (outv) {
                oc[(size_t)oy * W + dc] = (float)res;
            }
        }
    }
}

__global__ __launch_bounds__(NT, 3) void fgf_lane_kernel(
    const float* __restrict__ x, const float* __restrict__ y,
    float* __restrict__ out, int H, int W)
{
    const int c   = blockIdx.z;
    const int y0  = blockIdx.y * TY;
    const size_t plane = (size_t)H * (size_t)W;
    const float* xc = x + (size_t)c * plane;
    const float* yc = y + (size_t)c * plane;
    float* oc = out + (size_t)c * plane;

    const int l  = threadIdx.x;                       // lane 0..63
    const int wv = threadIdx.y;                       // wave 0..3
    const int out_base = blockIdx.x * BCOLS + wv * WCOLS;
    const int dc = out_base - 2 + l;                  // this lane's data column
    const int coli = iclamp(dc, 0, W - 1);
    const bool colv = (dc >= 0) && (dc < W);          // A-col validity
    const bool outv = (l >= 2) && (l <= 61) && (dc < W);

    double X[3], Y[3];          // rolling pixel rows (f64), slots by phase
    float  xn, yn;              // prefetched next row (f32)
    double CA[3][3], CB[3][3];  // rolling {L,R,F} combo rows (written S=0,1
                                // before first read at S=2)

    // prologue: slot1 <- row y0-2, slot2 <- row y0-1, xn/yn <- row y0
    {
        int r1 = iclamp(y0 - 2, 0, H - 1);
        int r2 = iclamp(y0 - 1, 0, H - 1);
        X[1] = (double)xc[(size_t)r1 * W + coli];
        Y[1] = (double)yc[(size_t)r1 * W + coli];
        X[2] = (double)xc[(size_t)r2 * W + coli];
        Y[2] = (double)yc[(size_t)r2 * W + coli];
        xn = xc[(size_t)y0 * W + coli];
        yn = yc[(size_t)y0 * W + coli];
    }

    // pipeline: S=0..TY+1; emits S=2..TY+1 (output rows y0..y0+TY-1)
    fgf_step<0, false, true>(0, y0, H, W, coli, colv, outv, dc, xc, yc, oc, X, Y, xn, yn, CA, CB);
    fgf_step<1, false, true>(1, y0, H, W, coli, colv, outv, dc, xc, yc, oc, X, Y, xn, yn, CA, CB);
#pragma unroll 1
    for (int sb = 0; sb < (TY - 3) / 3; sb++) {       // 9 triples: S=2..28
        const int S2 = 2 + 3 * sb;
        fgf_step<2, true, true>(S2,     y0, H, W, coli, colv, outv, dc, xc, yc, oc, X, Y, xn, yn, CA, CB);
        fgf_step<0, true, true>(S2 + 1, y0, H, W, coli, colv, outv, dc, xc, yc, oc, X, Y, xn, yn, CA, CB);
        fgf_step<1, true, true>(S2 + 2, y0, H, W, coli, colv, outv, dc, xc, yc, oc, X, Y, xn, yn, CA, CB);
    }
    fgf_step<2, true, true >(TY - 1, y0, H, W, coli, colv, outv, dc, xc, yc, oc, X, Y, xn, yn, CA, CB);
    fgf_step<0, true, true >(TY,     y0, H, W, coli, colv, outv, dc, xc, yc, oc, X, Y, xn, yn, CA, CB);
    fgf_step<1, true, false>(TY + 1, y0, H, W, coli, colv, outv, dc, xc, yc, oc, X, Y, xn, yn, CA, CB);
}

extern "C" void kernel_launch(void* const* d_in, const int* in_sizes, int n_in,
                              void* d_out, int out_size, void* d_ws, size_t ws_size,
                              hipStream_t stream) {
    const float* lr_x = (const float*)d_in[0];
    const float* lr_y = (const float*)d_in[1];
    // d_in[2] (hr_x) is dead in the reference computation.
    float* out = (float*)d_out;

    const int plane = in_sizes[0] / 3;
    const int H = (int)(0.5 + sqrt((double)plane));
    const int W = plane / H;

    dim3 block(64, 4, 1);
    dim3 grid((W + BCOLS - 1) / BCOLS, (H + TY - 1) / TY, 3);
    fgf_lane_kernel<<<grid, block, 0, stream>>>(lr_x, lr_y, out, H, W);
}